// Round 15
// baseline (489.786 us; speedup 1.0000x reference)
//
#include <hip/hip_runtime.h>
#include <hip/hip_bf16.h>
#include <stdint.h>

typedef __attribute__((ext_vector_type(8))) short bf16x8;
typedef __attribute__((ext_vector_type(4))) float f32x4;
typedef __attribute__((ext_vector_type(16))) float f32x16;

__device__ __forceinline__ unsigned short f2bf(float x) {
    union { float f; unsigned u; } u; u.f = x;
    unsigned r = u.u + 0x7FFFu + ((u.u >> 16) & 1u);
    return (unsigned short)(r >> 16);
}

// native packed f32->bf16 (gfx950 has no builtin; header fn is software RNE)
__device__ __forceinline__ unsigned pkbf(float a, float b) {
    unsigned r;
    asm("v_cvt_pk_bf16_f32 %0, %1, %2" : "=v"(r) : "v"(a), "v"(b));
    return r;
}

__device__ __forceinline__ float exp2a(float x) {
    float r; asm("v_exp_f32 %0, %1" : "=v"(r) : "v"(x)); return r;
}

__device__ __forceinline__ void gload_lds16(const void* g, void* s) {
    __builtin_amdgcn_global_load_lds(
        (const __attribute__((address_space(1))) void*)g,
        (__attribute__((address_space(3))) void*)s,
        16, 0, 0);
}

#define LOG2E 1.44269504088896f

// ---------------- fused prep: X cvt + 4 weight cvts + mask words -----------
__global__ void prep_kernel(const float* __restrict__ x,
                            const float* __restrict__ w0, const float* __restrict__ w1,
                            const float* __restrict__ w2, const float* __restrict__ w3,
                            const int* __restrict__ mask,
                            unsigned* __restrict__ xo,
                            unsigned* __restrict__ o0, unsigned* __restrict__ o1,
                            unsigned* __restrict__ o2, unsigned* __restrict__ o3,
                            unsigned long long* __restrict__ mw)
{
    int bid = blockIdx.x;
    if (bid < 8192) {
        int i = bid * 256 + threadIdx.x;
        float4 v = ((const float4*)x)[i];
        uint2 o;
        o.x = pkbf(v.x, v.y);
        o.y = pkbf(v.z, v.w);
        ((uint2*)xo)[i] = o;
    } else if (bid < 12288) {
        int j = (bid - 8192) * 256 + threadIdx.x;
        int w = j >> 18, jj = j & 262143;
        const float* src = (w == 0) ? w0 : (w == 1) ? w1 : (w == 2) ? w2 : w3;
        unsigned* dst = (w == 0) ? o0 : (w == 1) ? o1 : (w == 2) ? o2 : o3;
        float4 v = ((const float4*)src)[jj];
        uint2 o;
        o.x = pkbf(v.x, v.y);
        o.y = pkbf(v.z, v.w);
        ((uint2*)dst)[jj] = o;
    } else {
        int gw = (bid - 12288) * 4 + (threadIdx.x >> 6);
        int lane = threadIdx.x & 63;
        int b = gw >> 5, t = gw & 31;
        unsigned long long z = __ballot(mask[b * 2048 + t * 64 + lane] == 0);
        if (lane == 0) mw[gw] = z;
    }
}

// ---------------- fused QKV GEMM: C = X * W^T, bf16 in, fp32 acc ----------
// 1D grid 1536, XCD-grouping swizzle (r14-proven).
__global__ __launch_bounds__(256, 2)
void gemm_qkv(const short* __restrict__ X,
              const short* __restrict__ Wq, const short* __restrict__ Wk,
              const short* __restrict__ Wv,
              const float* __restrict__ bq, const float* __restrict__ bk,
              const float* __restrict__ bv,
              unsigned short* __restrict__ Qo, unsigned short* __restrict__ Ko,
              unsigned short* __restrict__ VTo)
{
    __shared__ short As[128 * 64];
    __shared__ short Bs[128 * 64];

    const int tid  = threadIdx.x;
    const int lane = tid & 63;
    const int wave = tid >> 6;

    const int bid = blockIdx.x;
    const int xcd = bid & 7;
    const int s   = bid >> 3;
    const int bxn = s >> 3;
    const int g   = s & 7;
    const int sel = bxn >> 3;
    const int bn  = (bxn & 7) * 128;
    const int bm  = (g * 8 + xcd) * 128;
    const int K = 1024;

    const short* B = (sel == 0) ? Wq : (sel == 1) ? Wk : Wv;
    const float* bias = (sel == 0) ? bq : (sel == 1) ? bk : bv;

    const int wm = (wave >> 1) * 64;
    const int wn = (wave & 1) * 64;

    f32x4 acc[4][4] = {};

    int sR[4], sC[4];
#pragma unroll
    for (int p = 0; p < 4; ++p) {
        int L = p * 4096 + tid * 16;
        int r = L >> 7;
        int c = (L & 127) ^ ((r & 7) << 4);
        sR[p] = r; sC[p] = c >> 1;
    }

    for (int k0 = 0; k0 < K; k0 += 64) {
        __syncthreads();
#pragma unroll
        for (int p = 0; p < 4; ++p) {
            gload_lds16(X + (size_t)(bm + sR[p]) * K + k0 + sC[p],
                        (char*)As + p * 4096 + wave * 1024);
            gload_lds16(B + (size_t)(bn + sR[p]) * K + k0 + sC[p],
                        (char*)Bs + p * 4096 + wave * 1024);
        }
        __syncthreads();
#pragma unroll
        for (int ks = 0; ks < 2; ++ks) {
            bf16x8 af[4];
#pragma unroll
            for (int m = 0; m < 4; ++m) {
                int row  = wm + m * 16 + (lane & 15);
                int boff = (ks * 64 + (lane >> 4) * 16) ^ ((row & 7) << 4);
                af[m] = *(const bf16x8*)((const char*)As + row * 128 + boff);
            }
#pragma unroll
            for (int n = 0; n < 4; ++n) {
                int row  = wn + n * 16 + (lane & 15);
                int boff = (ks * 64 + (lane >> 4) * 16) ^ ((row & 7) << 4);
                bf16x8 bfr = *(const bf16x8*)((const char*)Bs + row * 128 + boff);
#pragma unroll
                for (int m = 0; m < 4; ++m)
                    acc[m][n] = __builtin_amdgcn_mfma_f32_16x16x32_bf16(
                        af[m], bfr, acc[m][n], 0, 0, 0);
            }
        }
    }

    const int ccol  = lane & 15;
    const int crow0 = (lane >> 4) * 4;
#pragma unroll
    for (int n = 0; n < 4; ++n) {
        int gn = bn + wn + n * 16 + ccol;
        float bv2 = bias[gn];
        int h = gn >> 6, d = gn & 63;
#pragma unroll
        for (int m = 0; m < 4; ++m) {
            int gm0 = bm + wm + m * 16 + crow0;
            int b = gm0 >> 11, q = gm0 & 2047;
            if (sel == 2) {
                int g4 = (q >> 2) & 3;
                int qp = q ^ (((g4 + 1) & 2) ? 12 : 0);
                size_t base = ((size_t)(b * 16 + h) * 64 + d) * 2048 + qp;
                uint2 w2;
                w2.x = pkbf(acc[m][n][0] + bv2, acc[m][n][1] + bv2);
                w2.y = pkbf(acc[m][n][2] + bv2, acc[m][n][3] + bv2);
                *(uint2*)(VTo + base) = w2;
            } else {
                unsigned short* out = (sel == 0) ? Qo : Ko;
                float scale = (sel == 0) ? (0.125f * LOG2E) : 1.0f;
                size_t base = ((size_t)(b * 16 + h) * 2048 + q) * 64 + d;
#pragma unroll
                for (int r = 0; r < 4; ++r)
                    out[base + (size_t)r * 64] = f2bf((acc[m][n][r] + bv2) * scale);
            }
        }
    }
}

// ---------------- output projection GEMM: out fp32 = Ctx * Wo^T + bo ------
// 1D grid 512 (r14-proven coverage + XCD swizzle).
__global__ __launch_bounds__(256, 2)
void gemm_o(const short* __restrict__ A, const short* __restrict__ B,
            const float* __restrict__ bias, float* __restrict__ Out)
{
    __shared__ short As[128 * 64];
    __shared__ short Bs[128 * 64];

    const int tid  = threadIdx.x;
    const int lane = tid & 63;
    const int wave = tid >> 6;

    const int bid = blockIdx.x;
    const int xcd = bid & 7;
    const int s   = bid >> 3;
    const int bm  = ((s & 7) * 8 + xcd) * 128;
    const int bn  = (s >> 3) * 128;

    const int wm = (wave >> 1) * 64;
    const int wn = (wave & 1) * 64;
    const int K = 1024, N = 1024;

    f32x4 acc[4][4] = {};

    int sR[4], sC[4];
#pragma unroll
    for (int p = 0; p < 4; ++p) {
        int L = p * 4096 + tid * 16;
        int r = L >> 7;
        int c = (L & 127) ^ ((r & 7) << 4);
        sR[p] = r; sC[p] = c >> 1;
    }

    for (int k0 = 0; k0 < K; k0 += 64) {
        __syncthreads();
#pragma unroll
        for (int p = 0; p < 4; ++p) {
            gload_lds16(A + (size_t)(bm + sR[p]) * K + k0 + sC[p],
                        (char*)As + p * 4096 + wave * 1024);
            gload_lds16(B + (size_t)(bn + sR[p]) * K + k0 + sC[p],
                        (char*)Bs + p * 4096 + wave * 1024);
        }
        __syncthreads();
#pragma unroll
        for (int ks = 0; ks < 2; ++ks) {
            bf16x8 af[4];
#pragma unroll
            for (int m = 0; m < 4; ++m) {
                int row  = wm + m * 16 + (lane & 15);
                int boff = (ks * 64 + (lane >> 4) * 16) ^ ((row & 7) << 4);
                af[m] = *(const bf16x8*)((const char*)As + row * 128 + boff);
            }
#pragma unroll
            for (int n = 0; n < 4; ++n) {
                int row  = wn + n * 16 + (lane & 15);
                int boff = (ks * 64 + (lane >> 4) * 16) ^ ((row & 7) << 4);
                bf16x8 bfr = *(const bf16x8*)((const char*)Bs + row * 128 + boff);
#pragma unroll
                for (int m = 0; m < 4; ++m)
                    acc[m][n] = __builtin_amdgcn_mfma_f32_16x16x32_bf16(
                        af[m], bfr, acc[m][n], 0, 0, 0);
            }
        }
    }

    const int ccol  = lane & 15;
    const int crow0 = (lane >> 4) * 4;
#pragma unroll
    for (int n = 0; n < 4; ++n) {
        int gn = bn + wn + n * 16 + ccol;
        float bv = bias[gn];
#pragma unroll
        for (int m = 0; m < 4; ++m) {
            int gm0 = bm + wm + m * 16 + crow0;
#pragma unroll
            for (int r = 0; r < 4; ++r)
                Out[(size_t)(gm0 + r) * N + gn] = acc[m][n][r] + bv;
        }
    }
}

// ---------------- flash attention: K-split, 8 waves, in-block combine ------
// Q,K: bf16 [64][2048][64] (Q pre-scaled by log2e/8); VT: bf16 [64][64][2048]
// (k-permuted). ctx out bf16 [4][2048][1024].
// 8 waves: grp=wave>>2 handles KV tiles [grp*16, grp*16+16); w4=wave&3 gives
// q0 = qt*256 + w4*64 (m=2, 64 q-rows/wave — r11-proven datapath).
// No-max softmax makes (O, li) partials over disjoint K purely additive ->
// in-LDS combine at the end (no global round-trip).
// Per-group private 2-slot ring (race-free: barrier precedes stage).
// LDS: rings [0,64K) + li [64K,66K) + mz [66K,66.25K); combine-o reuses rings.
// launch_bounds(512,4): VGPR cap 128 (r11 body fits 128, no spills).
__global__ __launch_bounds__(512, 4)
void attn_kernel(const short* __restrict__ Q, const short* __restrict__ Kg,
                 const short* __restrict__ VTg,
                 const unsigned long long* __restrict__ mw,
                 unsigned short* __restrict__ ctx)
{
    __shared__ __align__(16) char lds[67840];
    unsigned long long* mzp = (unsigned long long*)(lds + 67584);

    const int tid  = threadIdx.x;
    const int lane = tid & 63;
    const int wave = tid >> 6;
    const int w4   = wave & 3;
    const int grp  = wave >> 2;
    const int l31  = lane & 31;
    const int hi   = lane >> 5;

    // XCD swizzle: 8 q-tiles of a (b,h) share one XCD's L2
    const int lin = blockIdx.y * 8 + blockIdx.x;   // gridDim = (8, 64)
    const int bh  = (lin & 7) * 8 + ((lin >> 3) & 7);
    const int qt  = lin >> 6;                      // [0,8)
    const int bb = bh >> 4, hh = bh & 15;

    const size_t hbase = (size_t)bh * (2048 * 64);
    const short* Qb  = Q   + hbase;
    const short* Kb  = Kg  + hbase;
    const short* VTb = VTg + hbase;      // [64][2048]
    const unsigned long long* mwb = mw + bb * 32;

    const int q0 = qt * 256 + w4 * 64;
    const int kbase = grp * 1024;        // this group's K range start

    // every wave writes all 32 mask words (identical values; self-visible)
    if (lane < 32) mzp[lane] = mwb[lane];

    // Q fragments (B-operand): col=q=lane&31, k^=hi*8+e
    bf16x8 qf[2][4];
#pragma unroll
    for (int m = 0; m < 2; ++m)
#pragma unroll
        for (int s = 0; s < 4; ++s) {
            int row = q0 + m * 32 + l31;
            qf[m][s] = *(const bf16x8*)(Qb + (size_t)row * 64 + s * 16 + hi * 8);
        }

    // per-lane LDS byte base within a K/V slot
    const int rb = hi * 1024 + l31 * 16;
    char* const ring = lds + grp * 32768;   // this group's 2 slots (16KB each)

    f32x16 o[2][2] = {};            // [m][nd]
    float li[2] = { 0.f, 0.f };

    // stage tile (kbase + t*64) into slot: K at ring+slot*16K, V at +8K
    auto stage = [&](int slot, int kt0) {
        char* ks = ring + slot * 16384;
#pragma unroll
        for (int p = 0; p < 2; ++p) {
            gload_lds16(Kb + (size_t)(kt0 + lane) * 64 + (p * 4 + w4) * 8,
                        ks + p * 4096 + w4 * 1024);
            gload_lds16(VTb + (size_t)lane * 2048 + kt0 + (p * 4 + w4) * 8,
                        ks + 8192 + p * 4096 + w4 * 1024);
        }
    };

    auto body = [&](int slot, int T) {   // T = global tile index (mask)
        const char* ks = ring + slot * 16384;
        const char* vt = ks + 8192;

        // ---- QK^T (swapped): S^T[k][q]; A-frag row=kt*32+l31, chunk=2s+hi ----
        f32x16 sA[2][2] = {};   // [m][kt]
        __builtin_amdgcn_s_setprio(1);
#pragma unroll
        for (int kt = 0; kt < 2; ++kt)
#pragma unroll
            for (int s = 0; s < 4; ++s) {
                bf16x8 kf = *(const bf16x8*)(ks + rb + s * 2048 + kt * 512);
                sA[0][kt] = __builtin_amdgcn_mfma_f32_32x32x16_bf16(kf, qf[0][s], sA[0][kt], 0, 0, 0);
                sA[1][kt] = __builtin_amdgcn_mfma_f32_32x32x16_bf16(kf, qf[1][s], sA[1][kt], 0, 0, 0);
            }
        __builtin_amdgcn_s_setprio(0);

        // ---- mask (uniform LDS word; all-ones -> branch never taken) ----
        const unsigned long long z = mzp[T];
        if (z) {
#pragma unroll
            for (int m = 0; m < 2; ++m)
#pragma unroll
                for (int kt = 0; kt < 2; ++kt)
#pragma unroll
                    for (int r = 0; r < 16; ++r) {
                        int k = kt * 32 + (r & 3) + 8 * (r >> 2) + (hi << 2);
                        if ((z >> k) & 1) sA[m][kt][r] = -3e38f;
                    }
        }

        // ---- no-max softmax: p = exp2(s); li += sum ----
        bf16x8 pa[2][2][2];     // [m][kt][sl]
#pragma unroll
        for (int m = 0; m < 2; ++m) {
#pragma unroll
            for (int kt = 0; kt < 2; ++kt)
#pragma unroll
                for (int r = 0; r < 16; ++r)
                    sA[m][kt][r] = exp2a(sA[m][kt][r]);

            f32x16 vs = sA[m][0] + sA[m][1];
            float s0 = vs[0] + vs[1],   s1 = vs[2] + vs[3];
            float s2 = vs[4] + vs[5],   s3 = vs[6] + vs[7];
            float s4 = vs[8] + vs[9],   s5 = vs[10] + vs[11];
            float s6 = vs[12] + vs[13], s7 = vs[14] + vs[15];
            float t0 = s0 + s1, t1 = s2 + s3, t2 = s4 + s5, t3 = s6 + s7;
            float sum = (t0 + t1) + (t2 + t3);
            sum += __shfl_xor(sum, 32, 64);
            li[m] += sum;

            // pack P -> A-frags: native v_cvt_pk_bf16_f32 (V^T pre-permuted)
#pragma unroll
            for (int kt = 0; kt < 2; ++kt) {
                union { unsigned u[4]; bf16x8 v; } f0, f1;
                f0.u[0] = pkbf(sA[m][kt][0],  sA[m][kt][1]);
                f0.u[1] = pkbf(sA[m][kt][2],  sA[m][kt][3]);
                f0.u[2] = pkbf(sA[m][kt][4],  sA[m][kt][5]);
                f0.u[3] = pkbf(sA[m][kt][6],  sA[m][kt][7]);
                f1.u[0] = pkbf(sA[m][kt][8],  sA[m][kt][9]);
                f1.u[1] = pkbf(sA[m][kt][10], sA[m][kt][11]);
                f1.u[2] = pkbf(sA[m][kt][12], sA[m][kt][13]);
                f1.u[3] = pkbf(sA[m][kt][14], sA[m][kt][15]);
                pa[m][kt][0] = f0.v;
                pa[m][kt][1] = f1.v;
            }
        }

        // ---- PV: O[q][d] += P * V; B-frag row=nd*32+l31, chunk=kt*4+sl*2+hi --
        __builtin_amdgcn_s_setprio(1);
#pragma unroll
        for (int kt = 0; kt < 2; ++kt)
#pragma unroll
            for (int sl = 0; sl < 2; ++sl) {
                bf16x8 vb[2];
#pragma unroll
                for (int nd = 0; nd < 2; ++nd)
                    vb[nd] = *(const bf16x8*)(vt + rb + (kt * 4 + sl * 2) * 1024 + nd * 512);
#pragma unroll
                for (int m = 0; m < 2; ++m)
#pragma unroll
                    for (int nd = 0; nd < 2; ++nd)
                        o[m][nd] = __builtin_amdgcn_mfma_f32_32x32x16_bf16(
                            pa[m][kt][sl], vb[nd], o[m][nd], 0, 0, 0);
            }
        __builtin_amdgcn_s_setprio(0);
    };

    // ---- main loop: 16 tiles per group, 2-slot ring, barrier-then-stage ----
    stage(0, kbase);
    for (int t = 0; t < 16; ++t) {
        asm volatile("s_waitcnt vmcnt(0)" ::: "memory");   // tile t landed
        __builtin_amdgcn_s_barrier();                      // slot (t+1)&1 free
        __builtin_amdgcn_sched_barrier(0);
        if (t + 1 < 16) stage((t + 1) & 1, kbase + (t + 1) * 64);
        body(t & 1, grp * 16 + t);
    }

    // ---- in-LDS combine: grp1 writes partials, grp0 adds ----
    __syncthreads();
    if (grp == 1) {
#pragma unroll
        for (int m = 0; m < 2; ++m)
#pragma unroll
            for (int nd = 0; nd < 2; ++nd)
#pragma unroll
                for (int g = 0; g < 4; ++g) {
                    float4 v = make_float4(o[m][nd][g * 4 + 0], o[m][nd][g * 4 + 1],
                                           o[m][nd][g * 4 + 2], o[m][nd][g * 4 + 3]);
                    *(float4*)(lds + w4 * 16384 + ((m * 2 + nd) * 4 + g) * 1024 + lane * 16) = v;
                }
        *(float2*)(lds + 65536 + w4 * 512 + lane * 8) = make_float2(li[0], li[1]);
    }
    __syncthreads();
    if (grp == 0) {
#pragma unroll
        for (int m = 0; m < 2; ++m)
#pragma unroll
            for (int nd = 0; nd < 2; ++nd)
#pragma unroll
                for (int g = 0; g < 4; ++g) {
                    float4 v = *(const float4*)(lds + w4 * 16384 + ((m * 2 + nd) * 4 + g) * 1024 + lane * 16);
                    o[m][nd][g * 4 + 0] += v.x;
                    o[m][nd][g * 4 + 1] += v.y;
                    o[m][nd][g * 4 + 2] += v.z;
                    o[m][nd][g * 4 + 3] += v.w;
                }
        float2 lv = *(const float2*)(lds + 65536 + w4 * 512 + lane * 8);
        li[0] += lv.x;
        li[1] += lv.y;

        // ---- epilogue: ctx[b][q][h*64+d] ----
#pragma unroll
        for (int m = 0; m < 2; ++m) {
            float rinv = 1.0f / li[m];
#pragma unroll
            for (int r = 0; r < 16; ++r) {
                int cr = (r & 3) + 8 * (r >> 2) + (hi << 2);
                float rv = __shfl(rinv, cr, 32);
                int q = q0 + m * 32 + cr;
#pragma unroll
                for (int nd = 0; nd < 2; ++nd) {
                    int d = hh * 64 + nd * 32 + l31;
                    ctx[((size_t)bb * 2048 + q) * 1024 + d] = f2bf(o[m][nd][r] * rv);
                }
            }
        }
    }
}

// ---------------- launcher ----------------
extern "C" void kernel_launch(void* const* d_in, const int* in_sizes, int n_in,
                              void* d_out, int out_size, void* d_ws, size_t ws_size,
                              hipStream_t stream)
{
    const float* x    = (const float*)d_in[0];
    const int*   mask = (const int*)d_in[1];
    const float* wq = (const float*)d_in[2];
    const float* bq = (const float*)d_in[3];
    const float* wk = (const float*)d_in[4];
    const float* bk = (const float*)d_in[5];
    const float* wv = (const float*)d_in[6];
    const float* bv = (const float*)d_in[7];
    const float* wo = (const float*)d_in[8];
    const float* bo = (const float*)d_in[9];
    float* out = (float*)d_out;

    char* ws = (char*)d_ws;
    short* Xb  = (short*)(ws + 0);               // 16 MB
    short* Wqb = (short*)(ws + (16ull << 20));   // 2 MB
    short* Wkb = (short*)(ws + (18ull << 20));
    short* Wvb = (short*)(ws + (20ull << 20));
    short* Wob = (short*)(ws + (22ull << 20));
    short* Qb  = (short*)(ws + (24ull << 20));   // 16 MB  [64][2048][64]
    short* Kb  = (short*)(ws + (40ull << 20));   // 16 MB  [64][2048][64]
    short* VT  = (short*)(ws + (56ull << 20));   // 16 MB  [64][64][2048] (k-permuted)
    short* Ctx = (short*)(ws + (72ull << 20));   // 16 MB
    unsigned long long* MW = (unsigned long long*)(ws + (88ull << 20)); // 1 KB

    prep_kernel<<<12320, 256, 0, stream>>>(
        x, wq, wk, wv, wo, mask,
        (unsigned*)Xb, (unsigned*)Wqb, (unsigned*)Wkb,
        (unsigned*)Wvb, (unsigned*)Wob, MW);

    gemm_qkv<<<1536, 256, 0, stream>>>(
        Xb, Wqb, Wkb, Wvb, bq, bk, bv,
        (unsigned short*)Qb, (unsigned short*)Kb, (unsigned short*)VT);

    attn_kernel<<<dim3(8, 64), 512, 0, stream>>>(Qb, Kb, VT, MW,
                                                 (unsigned short*)Ctx);

    gemm_o<<<512, 256, 0, stream>>>(Ctx, Wob, bo, out);
}

// Round 16
// 184.314 us; speedup vs baseline: 2.6573x; 2.6573x over previous
//
#include <hip/hip_runtime.h>
#include <hip/hip_bf16.h>
#include <stdint.h>

typedef __attribute__((ext_vector_type(8))) short bf16x8;
typedef __attribute__((ext_vector_type(4))) float f32x4;
typedef __attribute__((ext_vector_type(16))) float f32x16;

__device__ __forceinline__ unsigned short f2bf(float x) {
    union { float f; unsigned u; } u; u.f = x;
    unsigned r = u.u + 0x7FFFu + ((u.u >> 16) & 1u);
    return (unsigned short)(r >> 16);
}

// native packed f32->bf16 (gfx950 has no builtin; header fn is software RNE)
__device__ __forceinline__ unsigned pkbf(float a, float b) {
    unsigned r;
    asm("v_cvt_pk_bf16_f32 %0, %1, %2" : "=v"(r) : "v"(a), "v"(b));
    return r;
}

__device__ __forceinline__ float exp2a(float x) {
    float r; asm("v_exp_f32 %0, %1" : "=v"(r) : "v"(x)); return r;
}

__device__ __forceinline__ void gload_lds16(const void* g, void* s) {
    __builtin_amdgcn_global_load_lds(
        (const __attribute__((address_space(1))) void*)g,
        (__attribute__((address_space(3))) void*)s,
        16, 0, 0);
}

#define LOG2E 1.44269504088896f

// ---------------- fused prep: X cvt + 4 weight cvts + mask words -----------
__global__ void prep_kernel(const float* __restrict__ x,
                            const float* __restrict__ w0, const float* __restrict__ w1,
                            const float* __restrict__ w2, const float* __restrict__ w3,
                            const int* __restrict__ mask,
                            unsigned* __restrict__ xo,
                            unsigned* __restrict__ o0, unsigned* __restrict__ o1,
                            unsigned* __restrict__ o2, unsigned* __restrict__ o3,
                            unsigned long long* __restrict__ mw)
{
    int bid = blockIdx.x;
    if (bid < 8192) {
        int i = bid * 256 + threadIdx.x;
        float4 v = ((const float4*)x)[i];
        uint2 o;
        o.x = pkbf(v.x, v.y);
        o.y = pkbf(v.z, v.w);
        ((uint2*)xo)[i] = o;
    } else if (bid < 12288) {
        int j = (bid - 8192) * 256 + threadIdx.x;
        int w = j >> 18, jj = j & 262143;
        const float* src = (w == 0) ? w0 : (w == 1) ? w1 : (w == 2) ? w2 : w3;
        unsigned* dst = (w == 0) ? o0 : (w == 1) ? o1 : (w == 2) ? o2 : o3;
        float4 v = ((const float4*)src)[jj];
        uint2 o;
        o.x = pkbf(v.x, v.y);
        o.y = pkbf(v.z, v.w);
        ((uint2*)dst)[jj] = o;
    } else {
        int gw = (bid - 12288) * 4 + (threadIdx.x >> 6);
        int lane = threadIdx.x & 63;
        int b = gw >> 5, t = gw & 31;
        unsigned long long z = __ballot(mask[b * 2048 + t * 64 + lane] == 0);
        if (lane == 0) mw[gw] = z;
    }
}

// ---------------- fused QKV GEMM: C = X * W^T, bf16 in, fp32 acc ----------
// 1D grid 1536, XCD-grouping swizzle (r14-proven).
__global__ __launch_bounds__(256, 2)
void gemm_qkv(const short* __restrict__ X,
              const short* __restrict__ Wq, const short* __restrict__ Wk,
              const short* __restrict__ Wv,
              const float* __restrict__ bq, const float* __restrict__ bk,
              const float* __restrict__ bv,
              unsigned short* __restrict__ Qo, unsigned short* __restrict__ Ko,
              unsigned short* __restrict__ VTo)
{
    __shared__ short As[128 * 64];
    __shared__ short Bs[128 * 64];

    const int tid  = threadIdx.x;
    const int lane = tid & 63;
    const int wave = tid >> 6;

    const int bid = blockIdx.x;
    const int xcd = bid & 7;
    const int s   = bid >> 3;
    const int bxn = s >> 3;
    const int g   = s & 7;
    const int sel = bxn >> 3;
    const int bn  = (bxn & 7) * 128;
    const int bm  = (g * 8 + xcd) * 128;
    const int K = 1024;

    const short* B = (sel == 0) ? Wq : (sel == 1) ? Wk : Wv;
    const float* bias = (sel == 0) ? bq : (sel == 1) ? bk : bv;

    const int wm = (wave >> 1) * 64;
    const int wn = (wave & 1) * 64;

    f32x4 acc[4][4] = {};

    int sR[4], sC[4];
#pragma unroll
    for (int p = 0; p < 4; ++p) {
        int L = p * 4096 + tid * 16;
        int r = L >> 7;
        int c = (L & 127) ^ ((r & 7) << 4);
        sR[p] = r; sC[p] = c >> 1;
    }

    for (int k0 = 0; k0 < K; k0 += 64) {
        __syncthreads();
#pragma unroll
        for (int p = 0; p < 4; ++p) {
            gload_lds16(X + (size_t)(bm + sR[p]) * K + k0 + sC[p],
                        (char*)As + p * 4096 + wave * 1024);
            gload_lds16(B + (size_t)(bn + sR[p]) * K + k0 + sC[p],
                        (char*)Bs + p * 4096 + wave * 1024);
        }
        __syncthreads();
#pragma unroll
        for (int ks = 0; ks < 2; ++ks) {
            bf16x8 af[4];
#pragma unroll
            for (int m = 0; m < 4; ++m) {
                int row  = wm + m * 16 + (lane & 15);
                int boff = (ks * 64 + (lane >> 4) * 16) ^ ((row & 7) << 4);
                af[m] = *(const bf16x8*)((const char*)As + row * 128 + boff);
            }
#pragma unroll
            for (int n = 0; n < 4; ++n) {
                int row  = wn + n * 16 + (lane & 15);
                int boff = (ks * 64 + (lane >> 4) * 16) ^ ((row & 7) << 4);
                bf16x8 bfr = *(const bf16x8*)((const char*)Bs + row * 128 + boff);
#pragma unroll
                for (int m = 0; m < 4; ++m)
                    acc[m][n] = __builtin_amdgcn_mfma_f32_16x16x32_bf16(
                        af[m], bfr, acc[m][n], 0, 0, 0);
            }
        }
    }

    const int ccol  = lane & 15;
    const int crow0 = (lane >> 4) * 4;
#pragma unroll
    for (int n = 0; n < 4; ++n) {
        int gn = bn + wn + n * 16 + ccol;
        float bv2 = bias[gn];
        int h = gn >> 6, d = gn & 63;
#pragma unroll
        for (int m = 0; m < 4; ++m) {
            int gm0 = bm + wm + m * 16 + crow0;
            int b = gm0 >> 11, q = gm0 & 2047;
            if (sel == 2) {
                int g4 = (q >> 2) & 3;
                int qp = q ^ (((g4 + 1) & 2) ? 12 : 0);
                size_t base = ((size_t)(b * 16 + h) * 64 + d) * 2048 + qp;
                uint2 w2;
                w2.x = pkbf(acc[m][n][0] + bv2, acc[m][n][1] + bv2);
                w2.y = pkbf(acc[m][n][2] + bv2, acc[m][n][3] + bv2);
                *(uint2*)(VTo + base) = w2;
            } else {
                unsigned short* out = (sel == 0) ? Qo : Ko;
                float scale = (sel == 0) ? (0.125f * LOG2E) : 1.0f;
                size_t base = ((size_t)(b * 16 + h) * 2048 + q) * 64 + d;
#pragma unroll
                for (int r = 0; r < 4; ++r)
                    out[base + (size_t)r * 64] = f2bf((acc[m][n][r] + bv2) * scale);
            }
        }
    }
}

// ---------------- output projection GEMM: out fp32 = Ctx * Wo^T + bo ------
// 1D grid 512 (r14-proven coverage + XCD swizzle).
__global__ __launch_bounds__(256, 2)
void gemm_o(const short* __restrict__ A, const short* __restrict__ B,
            const float* __restrict__ bias, float* __restrict__ Out)
{
    __shared__ short As[128 * 64];
    __shared__ short Bs[128 * 64];

    const int tid  = threadIdx.x;
    const int lane = tid & 63;
    const int wave = tid >> 6;

    const int bid = blockIdx.x;
    const int xcd = bid & 7;
    const int s   = bid >> 3;
    const int bm  = ((s & 7) * 8 + xcd) * 128;
    const int bn  = (s >> 3) * 128;

    const int wm = (wave >> 1) * 64;
    const int wn = (wave & 1) * 64;
    const int K = 1024, N = 1024;

    f32x4 acc[4][4] = {};

    int sR[4], sC[4];
#pragma unroll
    for (int p = 0; p < 4; ++p) {
        int L = p * 4096 + tid * 16;
        int r = L >> 7;
        int c = (L & 127) ^ ((r & 7) << 4);
        sR[p] = r; sC[p] = c >> 1;
    }

    for (int k0 = 0; k0 < K; k0 += 64) {
        __syncthreads();
#pragma unroll
        for (int p = 0; p < 4; ++p) {
            gload_lds16(A + (size_t)(bm + sR[p]) * K + k0 + sC[p],
                        (char*)As + p * 4096 + wave * 1024);
            gload_lds16(B + (size_t)(bn + sR[p]) * K + k0 + sC[p],
                        (char*)Bs + p * 4096 + wave * 1024);
        }
        __syncthreads();
#pragma unroll
        for (int ks = 0; ks < 2; ++ks) {
            bf16x8 af[4];
#pragma unroll
            for (int m = 0; m < 4; ++m) {
                int row  = wm + m * 16 + (lane & 15);
                int boff = (ks * 64 + (lane >> 4) * 16) ^ ((row & 7) << 4);
                af[m] = *(const bf16x8*)((const char*)As + row * 128 + boff);
            }
#pragma unroll
            for (int n = 0; n < 4; ++n) {
                int row  = wn + n * 16 + (lane & 15);
                int boff = (ks * 64 + (lane >> 4) * 16) ^ ((row & 7) << 4);
                bf16x8 bfr = *(const bf16x8*)((const char*)Bs + row * 128 + boff);
#pragma unroll
                for (int m = 0; m < 4; ++m)
                    acc[m][n] = __builtin_amdgcn_mfma_f32_16x16x32_bf16(
                        af[m], bfr, acc[m][n], 0, 0, 0);
            }
        }
    }

    const int ccol  = lane & 15;
    const int crow0 = (lane >> 4) * 4;
#pragma unroll
    for (int n = 0; n < 4; ++n) {
        int gn = bn + wn + n * 16 + ccol;
        float bv = bias[gn];
#pragma unroll
        for (int m = 0; m < 4; ++m) {
            int gm0 = bm + wm + m * 16 + crow0;
#pragma unroll
            for (int r = 0; r < 4; ++r)
                Out[(size_t)(gm0 + r) * N + gn] = acc[m][n][r] + bv;
        }
    }
}

// ---------------- flash attention: K-split, 8 waves, in-block combine ------
// Identical structure to r15, but launch_bounds(512,2): empirically hipcc
// caps VGPR at 512/(2w), so w=2 -> 128 (r11-proven: body fits, no spills).
// r15's w=4 capped at 64 -> catastrophic scratch spills (778MB FETCH).
// Runtime occupancy: 128 VGPR -> 4 waves/SIMD; LDS 68KB*2=136KB<160KB ->
// 2 blocks/CU x 8 waves = 16 waves/CU (2x r14).
__global__ __launch_bounds__(512, 2)
void attn_kernel(const short* __restrict__ Q, const short* __restrict__ Kg,
                 const short* __restrict__ VTg,
                 const unsigned long long* __restrict__ mw,
                 unsigned short* __restrict__ ctx)
{
    __shared__ __align__(16) char lds[67840];
    unsigned long long* mzp = (unsigned long long*)(lds + 67584);

    const int tid  = threadIdx.x;
    const int lane = tid & 63;
    const int wave = tid >> 6;
    const int w4   = wave & 3;
    const int grp  = wave >> 2;
    const int l31  = lane & 31;
    const int hi   = lane >> 5;

    // XCD swizzle: 8 q-tiles of a (b,h) share one XCD's L2
    const int lin = blockIdx.y * 8 + blockIdx.x;   // gridDim = (8, 64)
    const int bh  = (lin & 7) * 8 + ((lin >> 3) & 7);
    const int qt  = lin >> 6;                      // [0,8)
    const int bb = bh >> 4, hh = bh & 15;

    const size_t hbase = (size_t)bh * (2048 * 64);
    const short* Qb  = Q   + hbase;
    const short* Kb  = Kg  + hbase;
    const short* VTb = VTg + hbase;      // [64][2048]
    const unsigned long long* mwb = mw + bb * 32;

    const int q0 = qt * 256 + w4 * 64;
    const int kbase = grp * 1024;        // this group's K range start

    // every wave writes all 32 mask words (identical values; self-visible)
    if (lane < 32) mzp[lane] = mwb[lane];

    // Q fragments (B-operand): col=q=lane&31, k^=hi*8+e
    bf16x8 qf[2][4];
#pragma unroll
    for (int m = 0; m < 2; ++m)
#pragma unroll
        for (int s = 0; s < 4; ++s) {
            int row = q0 + m * 32 + l31;
            qf[m][s] = *(const bf16x8*)(Qb + (size_t)row * 64 + s * 16 + hi * 8);
        }

    // per-lane LDS byte base within a K/V slot
    const int rb = hi * 1024 + l31 * 16;
    char* const ring = lds + grp * 32768;   // this group's 2 slots (16KB each)

    f32x16 o[2][2] = {};            // [m][nd]
    float li[2] = { 0.f, 0.f };

    // stage tile (kbase + t*64) into slot: K at ring+slot*16K, V at +8K
    auto stage = [&](int slot, int kt0) {
        char* ks = ring + slot * 16384;
#pragma unroll
        for (int p = 0; p < 2; ++p) {
            gload_lds16(Kb + (size_t)(kt0 + lane) * 64 + (p * 4 + w4) * 8,
                        ks + p * 4096 + w4 * 1024);
            gload_lds16(VTb + (size_t)lane * 2048 + kt0 + (p * 4 + w4) * 8,
                        ks + 8192 + p * 4096 + w4 * 1024);
        }
    };

    auto body = [&](int slot, int T) {   // T = global tile index (mask)
        const char* ks = ring + slot * 16384;
        const char* vt = ks + 8192;

        // ---- QK^T (swapped): S^T[k][q]; A-frag row=kt*32+l31, chunk=2s+hi ----
        f32x16 sA[2][2] = {};   // [m][kt]
        __builtin_amdgcn_s_setprio(1);
#pragma unroll
        for (int kt = 0; kt < 2; ++kt)
#pragma unroll
            for (int s = 0; s < 4; ++s) {
                bf16x8 kf = *(const bf16x8*)(ks + rb + s * 2048 + kt * 512);
                sA[0][kt] = __builtin_amdgcn_mfma_f32_32x32x16_bf16(kf, qf[0][s], sA[0][kt], 0, 0, 0);
                sA[1][kt] = __builtin_amdgcn_mfma_f32_32x32x16_bf16(kf, qf[1][s], sA[1][kt], 0, 0, 0);
            }
        __builtin_amdgcn_s_setprio(0);

        // ---- mask (uniform LDS word; all-ones -> branch never taken) ----
        const unsigned long long z = mzp[T];
        if (z) {
#pragma unroll
            for (int m = 0; m < 2; ++m)
#pragma unroll
                for (int kt = 0; kt < 2; ++kt)
#pragma unroll
                    for (int r = 0; r < 16; ++r) {
                        int k = kt * 32 + (r & 3) + 8 * (r >> 2) + (hi << 2);
                        if ((z >> k) & 1) sA[m][kt][r] = -3e38f;
                    }
        }

        // ---- no-max softmax: p = exp2(s); li += sum ----
        bf16x8 pa[2][2][2];     // [m][kt][sl]
#pragma unroll
        for (int m = 0; m < 2; ++m) {
#pragma unroll
            for (int kt = 0; kt < 2; ++kt)
#pragma unroll
                for (int r = 0; r < 16; ++r)
                    sA[m][kt][r] = exp2a(sA[m][kt][r]);

            f32x16 vs = sA[m][0] + sA[m][1];
            float s0 = vs[0] + vs[1],   s1 = vs[2] + vs[3];
            float s2 = vs[4] + vs[5],   s3 = vs[6] + vs[7];
            float s4 = vs[8] + vs[9],   s5 = vs[10] + vs[11];
            float s6 = vs[12] + vs[13], s7 = vs[14] + vs[15];
            float t0 = s0 + s1, t1 = s2 + s3, t2 = s4 + s5, t3 = s6 + s7;
            float sum = (t0 + t1) + (t2 + t3);
            sum += __shfl_xor(sum, 32, 64);
            li[m] += sum;

            // pack P -> A-frags: native v_cvt_pk_bf16_f32 (V^T pre-permuted)
#pragma unroll
            for (int kt = 0; kt < 2; ++kt) {
                union { unsigned u[4]; bf16x8 v; } f0, f1;
                f0.u[0] = pkbf(sA[m][kt][0],  sA[m][kt][1]);
                f0.u[1] = pkbf(sA[m][kt][2],  sA[m][kt][3]);
                f0.u[2] = pkbf(sA[m][kt][4],  sA[m][kt][5]);
                f0.u[3] = pkbf(sA[m][kt][6],  sA[m][kt][7]);
                f1.u[0] = pkbf(sA[m][kt][8],  sA[m][kt][9]);
                f1.u[1] = pkbf(sA[m][kt][10], sA[m][kt][11]);
                f1.u[2] = pkbf(sA[m][kt][12], sA[m][kt][13]);
                f1.u[3] = pkbf(sA[m][kt][14], sA[m][kt][15]);
                pa[m][kt][0] = f0.v;
                pa[m][kt][1] = f1.v;
            }
        }

        // ---- PV: O[q][d] += P * V; B-frag row=nd*32+l31, chunk=kt*4+sl*2+hi --
        __builtin_amdgcn_s_setprio(1);
#pragma unroll
        for (int kt = 0; kt < 2; ++kt)
#pragma unroll
            for (int sl = 0; sl < 2; ++sl) {
                bf16x8 vb[2];
#pragma unroll
                for (int nd = 0; nd < 2; ++nd)
                    vb[nd] = *(const bf16x8*)(vt + rb + (kt * 4 + sl * 2) * 1024 + nd * 512);
#pragma unroll
                for (int m = 0; m < 2; ++m)
#pragma unroll
                    for (int nd = 0; nd < 2; ++nd)
                        o[m][nd] = __builtin_amdgcn_mfma_f32_32x32x16_bf16(
                            pa[m][kt][sl], vb[nd], o[m][nd], 0, 0, 0);
            }
        __builtin_amdgcn_s_setprio(0);
    };

    // ---- main loop: 16 tiles per group, 2-slot ring, barrier-then-stage ----
    stage(0, kbase);
    for (int t = 0; t < 16; ++t) {
        asm volatile("s_waitcnt vmcnt(0)" ::: "memory");   // tile t landed
        __builtin_amdgcn_s_barrier();                      // slot (t+1)&1 free
        __builtin_amdgcn_sched_barrier(0);
        if (t + 1 < 16) stage((t + 1) & 1, kbase + (t + 1) * 64);
        body(t & 1, grp * 16 + t);
    }

    // ---- in-LDS combine: grp1 writes partials, grp0 adds ----
    __syncthreads();
    if (grp == 1) {
#pragma unroll
        for (int m = 0; m < 2; ++m)
#pragma unroll
            for (int nd = 0; nd < 2; ++nd)
#pragma unroll
                for (int g = 0; g < 4; ++g) {
                    float4 v = make_float4(o[m][nd][g * 4 + 0], o[m][nd][g * 4 + 1],
                                           o[m][nd][g * 4 + 2], o[m][nd][g * 4 + 3]);
                    *(float4*)(lds + w4 * 16384 + ((m * 2 + nd) * 4 + g) * 1024 + lane * 16) = v;
                }
        *(float2*)(lds + 65536 + w4 * 512 + lane * 8) = make_float2(li[0], li[1]);
    }
    __syncthreads();
    if (grp == 0) {
#pragma unroll
        for (int m = 0; m < 2; ++m)
#pragma unroll
            for (int nd = 0; nd < 2; ++nd)
#pragma unroll
                for (int g = 0; g < 4; ++g) {
                    float4 v = *(const float4*)(lds + w4 * 16384 + ((m * 2 + nd) * 4 + g) * 1024 + lane * 16);
                    o[m][nd][g * 4 + 0] += v.x;
                    o[m][nd][g * 4 + 1] += v.y;
                    o[m][nd][g * 4 + 2] += v.z;
                    o[m][nd][g * 4 + 3] += v.w;
                }
        float2 lv = *(const float2*)(lds + 65536 + w4 * 512 + lane * 8);
        li[0] += lv.x;
        li[1] += lv.y;

        // ---- epilogue: ctx[b][q][h*64+d] ----
#pragma unroll
        for (int m = 0; m < 2; ++m) {
            float rinv = 1.0f / li[m];
#pragma unroll
            for (int r = 0; r < 16; ++r) {
                int cr = (r & 3) + 8 * (r >> 2) + (hi << 2);
                float rv = __shfl(rinv, cr, 32);
                int q = q0 + m * 32 + cr;
#pragma unroll
                for (int nd = 0; nd < 2; ++nd) {
                    int d = hh * 64 + nd * 32 + l31;
                    ctx[((size_t)bb * 2048 + q) * 1024 + d] = f2bf(o[m][nd][r] * rv);
                }
            }
        }
    }
}

// ---------------- launcher ----------------
extern "C" void kernel_launch(void* const* d_in, const int* in_sizes, int n_in,
                              void* d_out, int out_size, void* d_ws, size_t ws_size,
                              hipStream_t stream)
{
    const float* x    = (const float*)d_in[0];
    const int*   mask = (const int*)d_in[1];
    const float* wq = (const float*)d_in[2];
    const float* bq = (const float*)d_in[3];
    const float* wk = (const float*)d_in[4];
    const float* bk = (const float*)d_in[5];
    const float* wv = (const float*)d_in[6];
    const float* bv = (const float*)d_in[7];
    const float* wo = (const float*)d_in[8];
    const float* bo = (const float*)d_in[9];
    float* out = (float*)d_out;

    char* ws = (char*)d_ws;
    short* Xb  = (short*)(ws + 0);               // 16 MB
    short* Wqb = (short*)(ws + (16ull << 20));   // 2 MB
    short* Wkb = (short*)(ws + (18ull << 20));
    short* Wvb = (short*)(ws + (20ull << 20));
    short* Wob = (short*)(ws + (22ull << 20));
    short* Qb  = (short*)(ws + (24ull << 20));   // 16 MB  [64][2048][64]
    short* Kb  = (short*)(ws + (40ull << 20));   // 16 MB  [64][2048][64]
    short* VT  = (short*)(ws + (56ull << 20));   // 16 MB  [64][64][2048] (k-permuted)
    short* Ctx = (short*)(ws + (72ull << 20));   // 16 MB
    unsigned long long* MW = (unsigned long long*)(ws + (88ull << 20)); // 1 KB

    prep_kernel<<<12320, 256, 0, stream>>>(
        x, wq, wk, wv, wo, mask,
        (unsigned*)Xb, (unsigned*)Wqb, (unsigned*)Wkb,
        (unsigned*)Wvb, (unsigned*)Wob, MW);

    gemm_qkv<<<1536, 256, 0, stream>>>(
        Xb, Wqb, Wkb, Wvb, bq, bk, bv,
        (unsigned short*)Qb, (unsigned short*)Kb, (unsigned short*)VT);

    attn_kernel<<<dim3(8, 64), 512, 0, stream>>>(Qb, Kb, VT, MW,
                                                 (unsigned short*)Ctx);

    gemm_o<<<512, 256, 0, stream>>>(Ctx, Wob, bo, out);
}

// Round 17
// 180.499 us; speedup vs baseline: 2.7135x; 1.0211x over previous
//
#include <hip/hip_runtime.h>
#include <hip/hip_bf16.h>
#include <stdint.h>

typedef __attribute__((ext_vector_type(8))) short bf16x8;
typedef __attribute__((ext_vector_type(4))) float f32x4;
typedef __attribute__((ext_vector_type(16))) float f32x16;

__device__ __forceinline__ unsigned short f2bf(float x) {
    union { float f; unsigned u; } u; u.f = x;
    unsigned r = u.u + 0x7FFFu + ((u.u >> 16) & 1u);
    return (unsigned short)(r >> 16);
}

// native packed f32->bf16 (gfx950 has no builtin; header fn is software RNE)
__device__ __forceinline__ unsigned pkbf(float a, float b) {
    unsigned r;
    asm("v_cvt_pk_bf16_f32 %0, %1, %2" : "=v"(r) : "v"(a), "v"(b));
    return r;
}

__device__ __forceinline__ float exp2a(float x) {
    float r; asm("v_exp_f32 %0, %1" : "=v"(r) : "v"(x)); return r;
}

__device__ __forceinline__ void gload_lds16(const void* g, void* s) {
    __builtin_amdgcn_global_load_lds(
        (const __attribute__((address_space(1))) void*)g,
        (__attribute__((address_space(3))) void*)s,
        16, 0, 0);
}

#define LOG2E 1.44269504088896f

// ---------------- fused prep: X cvt + 4 weight cvts + mask words -----------
__global__ void prep_kernel(const float* __restrict__ x,
                            const float* __restrict__ w0, const float* __restrict__ w1,
                            const float* __restrict__ w2, const float* __restrict__ w3,
                            const int* __restrict__ mask,
                            unsigned* __restrict__ xo,
                            unsigned* __restrict__ o0, unsigned* __restrict__ o1,
                            unsigned* __restrict__ o2, unsigned* __restrict__ o3,
                            unsigned long long* __restrict__ mw)
{
    int bid = blockIdx.x;
    if (bid < 8192) {
        int i = bid * 256 + threadIdx.x;
        float4 v = ((const float4*)x)[i];
        uint2 o;
        o.x = pkbf(v.x, v.y);
        o.y = pkbf(v.z, v.w);
        ((uint2*)xo)[i] = o;
    } else if (bid < 12288) {
        int j = (bid - 8192) * 256 + threadIdx.x;
        int w = j >> 18, jj = j & 262143;
        const float* src = (w == 0) ? w0 : (w == 1) ? w1 : (w == 2) ? w2 : w3;
        unsigned* dst = (w == 0) ? o0 : (w == 1) ? o1 : (w == 2) ? o2 : o3;
        float4 v = ((const float4*)src)[jj];
        uint2 o;
        o.x = pkbf(v.x, v.y);
        o.y = pkbf(v.z, v.w);
        ((uint2*)dst)[jj] = o;
    } else {
        int gw = (bid - 12288) * 4 + (threadIdx.x >> 6);
        int lane = threadIdx.x & 63;
        int b = gw >> 5, t = gw & 31;
        unsigned long long z = __ballot(mask[b * 2048 + t * 64 + lane] == 0);
        if (lane == 0) mw[gw] = z;
    }
}

// ---------------- fused QKV GEMM: C = X * W^T, bf16 in, fp32 acc ----------
// 1D grid 1536, XCD-grouping swizzle (r14-proven).
// 2-slot LDS ring, single barrier per K-step (r16-attn-proven pattern):
// vmcnt(0) [tile t landed] -> s_barrier -> stage(t+1) -> compute(t).
// Loads for t+1 overlap compute(t); slot (t+1)&1 was last read in
// compute(t-1) which precedes every wave's barrier(t) -> race-free.
__global__ __launch_bounds__(256, 2)
void gemm_qkv(const short* __restrict__ X,
              const short* __restrict__ Wq, const short* __restrict__ Wk,
              const short* __restrict__ Wv,
              const float* __restrict__ bq, const float* __restrict__ bk,
              const float* __restrict__ bv,
              unsigned short* __restrict__ Qo, unsigned short* __restrict__ Ko,
              unsigned short* __restrict__ VTo)
{
    __shared__ __align__(16) char lds[2][32768];   // [slot][A 16K | B 16K]

    const int tid  = threadIdx.x;
    const int lane = tid & 63;
    const int wave = tid >> 6;

    const int bid = blockIdx.x;
    const int xcd = bid & 7;
    const int s   = bid >> 3;
    const int bxn = s >> 3;
    const int g   = s & 7;
    const int sel = bxn >> 3;
    const int bn  = (bxn & 7) * 128;
    const int bm  = (g * 8 + xcd) * 128;
    const int K = 1024;

    const short* B = (sel == 0) ? Wq : (sel == 1) ? Wk : Wv;
    const float* bias = (sel == 0) ? bq : (sel == 1) ? bk : bv;

    const int wm = (wave >> 1) * 64;
    const int wn = (wave & 1) * 64;

    f32x4 acc[4][4] = {};

    int sR[4], sC[4];
#pragma unroll
    for (int p = 0; p < 4; ++p) {
        int L = p * 4096 + tid * 16;
        int r = L >> 7;
        int c = (L & 127) ^ ((r & 7) << 4);
        sR[p] = r; sC[p] = c >> 1;
    }

    auto stageT = [&](int slot, int k0) {
#pragma unroll
        for (int p = 0; p < 4; ++p) {
            gload_lds16(X + (size_t)(bm + sR[p]) * K + k0 + sC[p],
                        &lds[slot][0] + p * 4096 + wave * 1024);
            gload_lds16(B + (size_t)(bn + sR[p]) * K + k0 + sC[p],
                        &lds[slot][16384] + p * 4096 + wave * 1024);
        }
    };

    stageT(0, 0);
    for (int t = 0; t < 16; ++t) {
        asm volatile("s_waitcnt vmcnt(0)" ::: "memory");   // tile t landed
        __builtin_amdgcn_s_barrier();
        __builtin_amdgcn_sched_barrier(0);
        if (t + 1 < 16) stageT((t + 1) & 1, (t + 1) * 64); // overlaps compute(t)
        const char* As = &lds[t & 1][0];
        const char* Bs = &lds[t & 1][16384];
#pragma unroll
        for (int ks = 0; ks < 2; ++ks) {
            bf16x8 af[4];
#pragma unroll
            for (int m = 0; m < 4; ++m) {
                int row  = wm + m * 16 + (lane & 15);
                int boff = (ks * 64 + (lane >> 4) * 16) ^ ((row & 7) << 4);
                af[m] = *(const bf16x8*)(As + row * 128 + boff);
            }
#pragma unroll
            for (int n = 0; n < 4; ++n) {
                int row  = wn + n * 16 + (lane & 15);
                int boff = (ks * 64 + (lane >> 4) * 16) ^ ((row & 7) << 4);
                bf16x8 bfr = *(const bf16x8*)(Bs + row * 128 + boff);
#pragma unroll
                for (int m = 0; m < 4; ++m)
                    acc[m][n] = __builtin_amdgcn_mfma_f32_16x16x32_bf16(
                        af[m], bfr, acc[m][n], 0, 0, 0);
            }
        }
    }

    const int ccol  = lane & 15;
    const int crow0 = (lane >> 4) * 4;
#pragma unroll
    for (int n = 0; n < 4; ++n) {
        int gn = bn + wn + n * 16 + ccol;
        float bv2 = bias[gn];
        int h = gn >> 6, d = gn & 63;
#pragma unroll
        for (int m = 0; m < 4; ++m) {
            int gm0 = bm + wm + m * 16 + crow0;
            int b = gm0 >> 11, q = gm0 & 2047;
            if (sel == 2) {
                int g4 = (q >> 2) & 3;
                int qp = q ^ (((g4 + 1) & 2) ? 12 : 0);
                size_t base = ((size_t)(b * 16 + h) * 64 + d) * 2048 + qp;
                uint2 w2;
                w2.x = pkbf(acc[m][n][0] + bv2, acc[m][n][1] + bv2);
                w2.y = pkbf(acc[m][n][2] + bv2, acc[m][n][3] + bv2);
                *(uint2*)(VTo + base) = w2;
            } else {
                unsigned short* out = (sel == 0) ? Qo : Ko;
                float scale = (sel == 0) ? (0.125f * LOG2E) : 1.0f;
                size_t base = ((size_t)(b * 16 + h) * 2048 + q) * 64 + d;
#pragma unroll
                for (int r = 0; r < 4; ++r)
                    out[base + (size_t)r * 64] = f2bf((acc[m][n][r] + bv2) * scale);
            }
        }
    }
}

// ---------------- output projection GEMM: out fp32 = Ctx * Wo^T + bo ------
// 1D grid 512, XCD swizzle (r14-proven); same 2-slot ring as gemm_qkv.
__global__ __launch_bounds__(256, 2)
void gemm_o(const short* __restrict__ A, const short* __restrict__ B,
            const float* __restrict__ bias, float* __restrict__ Out)
{
    __shared__ __align__(16) char lds[2][32768];

    const int tid  = threadIdx.x;
    const int lane = tid & 63;
    const int wave = tid >> 6;

    const int bid = blockIdx.x;
    const int xcd = bid & 7;
    const int s   = bid >> 3;
    const int bm  = ((s & 7) * 8 + xcd) * 128;
    const int bn  = (s >> 3) * 128;

    const int wm = (wave >> 1) * 64;
    const int wn = (wave & 1) * 64;
    const int K = 1024, N = 1024;

    f32x4 acc[4][4] = {};

    int sR[4], sC[4];
#pragma unroll
    for (int p = 0; p < 4; ++p) {
        int L = p * 4096 + tid * 16;
        int r = L >> 7;
        int c = (L & 127) ^ ((r & 7) << 4);
        sR[p] = r; sC[p] = c >> 1;
    }

    auto stageT = [&](int slot, int k0) {
#pragma unroll
        for (int p = 0; p < 4; ++p) {
            gload_lds16(A + (size_t)(bm + sR[p]) * K + k0 + sC[p],
                        &lds[slot][0] + p * 4096 + wave * 1024);
            gload_lds16(B + (size_t)(bn + sR[p]) * K + k0 + sC[p],
                        &lds[slot][16384] + p * 4096 + wave * 1024);
        }
    };

    stageT(0, 0);
    for (int t = 0; t < 16; ++t) {
        asm volatile("s_waitcnt vmcnt(0)" ::: "memory");
        __builtin_amdgcn_s_barrier();
        __builtin_amdgcn_sched_barrier(0);
        if (t + 1 < 16) stageT((t + 1) & 1, (t + 1) * 64);
        const char* As = &lds[t & 1][0];
        const char* Bs = &lds[t & 1][16384];
#pragma unroll
        for (int ks = 0; ks < 2; ++ks) {
            bf16x8 af[4];
#pragma unroll
            for (int m = 0; m < 4; ++m) {
                int row  = wm + m * 16 + (lane & 15);
                int boff = (ks * 64 + (lane >> 4) * 16) ^ ((row & 7) << 4);
                af[m] = *(const bf16x8*)(As + row * 128 + boff);
            }
#pragma unroll
            for (int n = 0; n < 4; ++n) {
                int row  = wn + n * 16 + (lane & 15);
                int boff = (ks * 64 + (lane >> 4) * 16) ^ ((row & 7) << 4);
                bf16x8 bfr = *(const bf16x8*)(Bs + row * 128 + boff);
#pragma unroll
                for (int m = 0; m < 4; ++m)
                    acc[m][n] = __builtin_amdgcn_mfma_f32_16x16x32_bf16(
                        af[m], bfr, acc[m][n], 0, 0, 0);
            }
        }
    }

    const int ccol  = lane & 15;
    const int crow0 = (lane >> 4) * 4;
#pragma unroll
    for (int n = 0; n < 4; ++n) {
        int gn = bn + wn + n * 16 + ccol;
        float bv = bias[gn];
#pragma unroll
        for (int m = 0; m < 4; ++m) {
            int gm0 = bm + wm + m * 16 + crow0;
#pragma unroll
            for (int r = 0; r < 4; ++r)
                Out[(size_t)(gm0 + r) * N + gn] = acc[m][n][r] + bv;
        }
    }
}

// ---------------- flash attention (r14-proven: 32x32 mfma, 3-slot ring) ----
// Q,K: bf16 [64][2048][64] (Q pre-scaled by log2e/8); VT: bf16 [64][64][2048]
// (k-permuted). mw: mask ballot words. ctx out bf16 [4][2048][1024]
// m=2 (64 q-rows/wave), grid (8,64). Chunked conflict-free LDS (r8).
__global__ __launch_bounds__(256, 2)
void attn_kernel(const short* __restrict__ Q, const short* __restrict__ Kg,
                 const short* __restrict__ VTg,
                 const unsigned long long* __restrict__ mw,
                 unsigned short* __restrict__ ctx)
{
    __shared__ __align__(16) short Ks[3][4096];   // 8KB/slot: [c][row] 16B units
    __shared__ __align__(16) short Vt[3][4096];   // 8KB/slot: [c][d-row]
    __shared__ unsigned long long mz[32];

    const int tid  = threadIdx.x;
    const int lane = tid & 63;
    const int wave = tid >> 6;
    const int l31  = lane & 31;
    const int hi   = lane >> 5;

    // XCD swizzle: 8 q-tiles of a (b,h) share one XCD's L2
    const int lin = blockIdx.y * 8 + blockIdx.x;   // gridDim = (8, 64)
    const int bh  = (lin & 7) * 8 + ((lin >> 3) & 7);
    const int qt  = lin >> 6;
    const int bb = bh >> 4, hh = bh & 15;

    const size_t hbase = (size_t)bh * (2048 * 64);
    const short* Qb  = Q   + hbase;
    const short* Kb  = Kg  + hbase;
    const short* VTb = VTg + hbase;      // [64][2048]
    const unsigned long long* mwb = mw + bb * 32;

    const int q0 = qt * 256 + wave * 64;

    if (lane < 32) mz[lane] = mwb[lane];

    bf16x8 qf[2][4];
#pragma unroll
    for (int m = 0; m < 2; ++m)
#pragma unroll
        for (int s = 0; s < 4; ++s) {
            int row = q0 + m * 32 + l31;
            qf[m][s] = *(const bf16x8*)(Qb + (size_t)row * 64 + s * 16 + hi * 8);
        }

    const int rb = hi * 1024 + l31 * 16;

    f32x16 o[2][2] = {};
    float li[2] = { 0.f, 0.f };

    auto stage = [&](int slot, int kt0) {
#pragma unroll
        for (int p = 0; p < 2; ++p) {
            gload_lds16(Kb + (size_t)(kt0 + lane) * 64 + (p * 4 + wave) * 8,
                        (char*)&Ks[slot][0] + p * 4096 + wave * 1024);
            gload_lds16(VTb + (size_t)lane * 2048 + kt0 + (p * 4 + wave) * 8,
                        (char*)&Vt[slot][0] + p * 4096 + wave * 1024);
        }
    };

    auto body = [&](int slot, int t) {
        const char* ks = (const char*)&Ks[slot][0];
        const char* vt = (const char*)&Vt[slot][0];

        f32x16 sA[2][2] = {};
        __builtin_amdgcn_s_setprio(1);
#pragma unroll
        for (int kt = 0; kt < 2; ++kt)
#pragma unroll
            for (int s = 0; s < 4; ++s) {
                bf16x8 kf = *(const bf16x8*)(ks + rb + s * 2048 + kt * 512);
                sA[0][kt] = __builtin_amdgcn_mfma_f32_32x32x16_bf16(kf, qf[0][s], sA[0][kt], 0, 0, 0);
                sA[1][kt] = __builtin_amdgcn_mfma_f32_32x32x16_bf16(kf, qf[1][s], sA[1][kt], 0, 0, 0);
            }
        __builtin_amdgcn_s_setprio(0);

        const unsigned long long z = mz[t];
        if (z) {
#pragma unroll
            for (int m = 0; m < 2; ++m)
#pragma unroll
                for (int kt = 0; kt < 2; ++kt)
#pragma unroll
                    for (int r = 0; r < 16; ++r) {
                        int k = kt * 32 + (r & 3) + 8 * (r >> 2) + (hi << 2);
                        if ((z >> k) & 1) sA[m][kt][r] = -3e38f;
                    }
        }

        bf16x8 pa[2][2][2];
#pragma unroll
        for (int m = 0; m < 2; ++m) {
#pragma unroll
            for (int kt = 0; kt < 2; ++kt)
#pragma unroll
                for (int r = 0; r < 16; ++r)
                    sA[m][kt][r] = exp2a(sA[m][kt][r]);

            f32x16 vs = sA[m][0] + sA[m][1];
            float s0 = vs[0] + vs[1],   s1 = vs[2] + vs[3];
            float s2 = vs[4] + vs[5],   s3 = vs[6] + vs[7];
            float s4 = vs[8] + vs[9],   s5 = vs[10] + vs[11];
            float s6 = vs[12] + vs[13], s7 = vs[14] + vs[15];
            float t0 = s0 + s1, t1 = s2 + s3, t2 = s4 + s5, t3 = s6 + s7;
            float sum = (t0 + t1) + (t2 + t3);
            sum += __shfl_xor(sum, 32, 64);
            li[m] += sum;

#pragma unroll
            for (int kt = 0; kt < 2; ++kt) {
                union { unsigned u[4]; bf16x8 v; } f0, f1;
                f0.u[0] = pkbf(sA[m][kt][0],  sA[m][kt][1]);
                f0.u[1] = pkbf(sA[m][kt][2],  sA[m][kt][3]);
                f0.u[2] = pkbf(sA[m][kt][4],  sA[m][kt][5]);
                f0.u[3] = pkbf(sA[m][kt][6],  sA[m][kt][7]);
                f1.u[0] = pkbf(sA[m][kt][8],  sA[m][kt][9]);
                f1.u[1] = pkbf(sA[m][kt][10], sA[m][kt][11]);
                f1.u[2] = pkbf(sA[m][kt][12], sA[m][kt][13]);
                f1.u[3] = pkbf(sA[m][kt][14], sA[m][kt][15]);
                pa[m][kt][0] = f0.v;
                pa[m][kt][1] = f1.v;
            }
        }

        __builtin_amdgcn_s_setprio(1);
#pragma unroll
        for (int kt = 0; kt < 2; ++kt)
#pragma unroll
            for (int sl = 0; sl < 2; ++sl) {
                bf16x8 vb[2];
#pragma unroll
                for (int nd = 0; nd < 2; ++nd)
                    vb[nd] = *(const bf16x8*)(vt + rb + (kt * 4 + sl * 2) * 1024 + nd * 512);
#pragma unroll
                for (int m = 0; m < 2; ++m)
#pragma unroll
                    for (int nd = 0; nd < 2; ++nd)
                        o[m][nd] = __builtin_amdgcn_mfma_f32_32x32x16_bf16(
                            pa[m][kt][sl], vb[nd], o[m][nd], 0, 0, 0);
            }
        __builtin_amdgcn_s_setprio(0);
    };

    stage(0, 0);

    for (int t = 0; t < 31; ++t) {
        stage((t + 1) % 3, (t + 1) * 64);             // tile t+1 in flight
        asm volatile("s_waitcnt vmcnt(4)" ::: "memory");  // tile t landed
        __builtin_amdgcn_s_barrier();
        __builtin_amdgcn_sched_barrier(0);
        body(t % 3, t);
    }
    asm volatile("s_waitcnt vmcnt(0)" ::: "memory");      // last tile landed
    __builtin_amdgcn_s_barrier();
    __builtin_amdgcn_sched_barrier(0);
    body(31 % 3, 31);

#pragma unroll
    for (int m = 0; m < 2; ++m) {
        float rinv = 1.0f / li[m];
#pragma unroll
        for (int r = 0; r < 16; ++r) {
            int cr = (r & 3) + 8 * (r >> 2) + (hi << 2);
            float rv = __shfl(rinv, cr, 32);
            int q = q0 + m * 32 + cr;
#pragma unroll
            for (int nd = 0; nd < 2; ++nd) {
                int d = hh * 64 + nd * 32 + l31;
                ctx[((size_t)bb * 2048 + q) * 1024 + d] = f2bf(o[m][nd][r] * rv);
            }
        }
    }
}

// ---------------- launcher ----------------
extern "C" void kernel_launch(void* const* d_in, const int* in_sizes, int n_in,
                              void* d_out, int out_size, void* d_ws, size_t ws_size,
                              hipStream_t stream)
{
    const float* x    = (const float*)d_in[0];
    const int*   mask = (const int*)d_in[1];
    const float* wq = (const float*)d_in[2];
    const float* bq = (const float*)d_in[3];
    const float* wk = (const float*)d_in[4];
    const float* bk = (const float*)d_in[5];
    const float* wv = (const float*)d_in[6];
    const float* bv = (const float*)d_in[7];
    const float* wo = (const float*)d_in[8];
    const float* bo = (const float*)d_in[9];
    float* out = (float*)d_out;

    char* ws = (char*)d_ws;
    short* Xb  = (short*)(ws + 0);               // 16 MB
    short* Wqb = (short*)(ws + (16ull << 20));   // 2 MB
    short* Wkb = (short*)(ws + (18ull << 20));
    short* Wvb = (short*)(ws + (20ull << 20));
    short* Wob = (short*)(ws + (22ull << 20));
    short* Qb  = (short*)(ws + (24ull << 20));   // 16 MB  [64][2048][64]
    short* Kb  = (short*)(ws + (40ull << 20));   // 16 MB  [64][2048][64]
    short* VT  = (short*)(ws + (56ull << 20));   // 16 MB  [64][64][2048] (k-permuted)
    short* Ctx = (short*)(ws + (72ull << 20));   // 16 MB
    unsigned long long* MW = (unsigned long long*)(ws + (88ull << 20)); // 1 KB

    prep_kernel<<<12320, 256, 0, stream>>>(
        x, wq, wk, wv, wo, mask,
        (unsigned*)Xb, (unsigned*)Wqb, (unsigned*)Wkb,
        (unsigned*)Wvb, (unsigned*)Wob, MW);

    gemm_qkv<<<1536, 256, 0, stream>>>(
        Xb, Wqb, Wkb, Wvb, bq, bk, bv,
        (unsigned short*)Qb, (unsigned short*)Kb, (unsigned short*)VT);

    attn_kernel<<<dim3(8, 64), 256, 0, stream>>>(Qb, Kb, VT, MW,
                                                 (unsigned short*)Ctx);

    gemm_o<<<512, 256, 0, stream>>>(Ctx, Wob, bo, out);
}